// Round 11
// baseline (4627.032 us; speedup 1.0000x reference)
//
#include <hip/hip_runtime.h>
#include <cstdint>
#include <cstddef>

// Autoregressive 3-layer LSTM, B=512, T=75, IN=96, H=1024, bf16 MFMA compute.
// R11: DEPTH-5 PREFETCH / 6-BUFFER LDS RING (144KB) on the R10 skeleton.
//   R10 post-mortem: A-read policy neutral; Little's-law audit says the K-loop
//   is inflight-limited: 72KB in flight per CU at ~2.2us effective fabric
//   latency == measured 33.5GB/s/CU staging BW. R9 (more waves, same inflight)
//   and R5/R10 (traffic policy, same inflight) were all neutral -- consistent.
//   Lever: in-flight bytes 72KB -> 120KB (ring 4->6 bufs, depth 3->5,
//   vmcnt 15/12/9/6/3/0). Ring hazard: stage@t writes buf (t+5)%6=(t-1)%6,
//   readers passed end-of-(t-1) barrier first -- same invariant as 4-ring.
//   Memory scheme unchanged from R10: cached A+W, per-step acquire fence at
//   FC sync, write-through agent-atomic h/x, fence-free two-level barrier.
// GEMM stage: 64x128 gate-grouped tile, BK=64, 8 waves (2/SIMD), XOR-swizzled
// LDS, fused cell epilogue; c-state in registers.

typedef unsigned short u16;
typedef float v4f __attribute__((ext_vector_type(4)));
typedef short v8s __attribute__((ext_vector_type(8)));    // 8 bf16 (4 VGPRs)
typedef u16   v8u16 __attribute__((ext_vector_type(8)));

#define BATCH 512
#define H_DIM 1024
#define GATES 4096
#define T_STEPS 75
#define IN_DIM 96
#define K0P 1152              // layer0 K padded: 96 + 1024 + 32 zeros
#define K12 2048              // layers 1,2 K: 1024 + 1024
#define NBLK 256
#define NBUF 6                // LDS ring depth (staging pipeline = NBUF-1)

__device__ __forceinline__ float bf2f(u16 u) {
    unsigned int x = ((unsigned int)u) << 16;
    return __builtin_bit_cast(float, x);
}
__device__ __forceinline__ u16 f2bf(float f) {   // round-to-nearest-even
    unsigned int x = __builtin_bit_cast(unsigned int, f);
    x += 0x7fffu + ((x >> 16) & 1u);
    return (u16)(x >> 16);
}
// cached global->LDS (W: x8 panel dedup; A: x4 m-block dedup per XCD)
__device__ __forceinline__ void gload16(const void* g, void* l) {
    __builtin_amdgcn_global_load_lds(
        (const __attribute__((address_space(1))) void*)g,
        (__attribute__((address_space(3))) void*)l, 16, 0, 0);
}
__device__ __forceinline__ void st_agent_u32(unsigned int* p, unsigned int v) {
    __hip_atomic_store(p, v, __ATOMIC_RELAXED, __HIP_MEMORY_SCOPE_AGENT);
}
__device__ __forceinline__ unsigned int ld_agent_u32(const unsigned int* p) {
    return __hip_atomic_load(p, __ATOMIC_RELAXED, __HIP_MEMORY_SCOPE_AGENT);
}

// ---- two-level grid barrier, contention-separated (R7, proven) ----
// acq=true (once per step, FC sync): per-block acquire fence (L1/L2 inv)
// AFTER the wait -> kills any same-parity stale activation lines.
__device__ __forceinline__ void grid_sync(int* bar, int g, bool acq) {
    __syncthreads();   // all waves: s_waitcnt vmcnt(0) -> stores visible
    if (threadIdx.x == 0) {
        int old = __hip_atomic_fetch_add(&bar[(blockIdx.x & 7) * 32], 1,
                                         __ATOMIC_RELAXED, __HIP_MEMORY_SCOPE_AGENT);
        if (old + 1 == 32 * g) {            // this block completed its group
            int r = __hip_atomic_fetch_add(&bar[256], 1,
                                           __ATOMIC_RELAXED, __HIP_MEMORY_SCOPE_AGENT);
            if (r + 1 == 8 * g)             // all groups complete
                __hip_atomic_store(&bar[288], g,
                                   __ATOMIC_RELAXED, __HIP_MEMORY_SCOPE_AGENT);
        }
        int spins = 0;
        while (__hip_atomic_load(&bar[288],
                                 __ATOMIC_RELAXED, __HIP_MEMORY_SCOPE_AGENT) < g) {
            if (++spins > (1 << 17)) break;   // watchdog: fail fast, not hang
            __builtin_amdgcn_s_sleep(1);
        }
        if (acq)
            __builtin_amdgcn_fence(__ATOMIC_ACQUIRE, "agent");   // inv L1/L2
    }
    __syncthreads();
}

// ---- fused gates-GEMM + LSTM cell stage ----
// block tile 64 rows x (4 gates x 32 j), 8 waves (4m x 2n), BK=64.
__device__ __forceinline__ void gemm_stage(
    char* smem, const u16* __restrict__ A, const u16* __restrict__ W,
    int K, int nk, v4f bv, v4f& cc,
    u16* __restrict__ h1, int h1s, u16* __restrict__ h2, int h2s,
    int bm, int j0)
{
    u16* sA = (u16*)smem;                      // NBUF x 4096 u16 (64x64, 8KB)
    u16* sB = (u16*)(smem + NBUF * 8192);      // NBUF x 8192 u16 (128x64, 16KB)

    const int tid  = threadIdx.x;
    const int lane = tid & 63;
    const int wid  = tid >> 6;          // 0..7
    const int wm   = (wid >> 1) * 16;   // wave m-offset: 0,16,32,48
    const int wn   = (wid & 1) * 64;    // wave n-offset: 0,64
    const int l15  = lane & 15;
    const int lq   = lane >> 4;         // 0..3

    v4f acc[4];
    #pragma unroll
    for (int nf = 0; nf < 4; ++nf) {
        v4f tv = {bv[nf], bv[nf], bv[nf], bv[nf]};
        acc[nf] = tv;
    }

    const int srow = tid >> 3;                                   // 0..63
    const int kcs  = ((tid & 7) ^ (srow & 7)) << 3;              // swizzled src k-elem

    auto stage = [&](int b, int k0) {
        u16* sa = sA + b * 4096;
        u16* sb = sB + b * 8192;
        gload16(A + (size_t)(bm + srow) * K + k0 + kcs, sa + tid * 8);
        #pragma unroll
        for (int q = 0; q < 2; ++q) {
            const int fr = q * 64 + srow;            // 0..127
            gload16(W + (size_t)((fr >> 5) * H_DIM + j0 + (fr & 31)) * K + k0 + kcs,
                    sb + q * 4096 + tid * 8);
        }
    };

    // depth-5 prologue (3 loads/thread/tile -> 15 outstanding)
    {
        const int npre = nk < (NBUF - 1) ? nk : (NBUF - 1);
        for (int p = 0; p < npre; ++p) stage(p, p * 64);
    }

    int cur = 0;
    int stg = NBUF - 1;      // (tt + NBUF-1) % NBUF, tracked by rotation
    #pragma unroll 1
    for (int tt = 0; tt < nk; ++tt) {
        if (tt + (NBUF - 1) < nk) stage(stg, (tt + (NBUF - 1)) * 64);
        const int ahead = (nk - 1 - tt) < (NBUF - 1) ? (nk - 1 - tt) : (NBUF - 1);
        if (ahead == 5)      asm volatile("s_waitcnt vmcnt(15)" ::: "memory");
        else if (ahead == 4) asm volatile("s_waitcnt vmcnt(12)" ::: "memory");
        else if (ahead == 3) asm volatile("s_waitcnt vmcnt(9)"  ::: "memory");
        else if (ahead == 2) asm volatile("s_waitcnt vmcnt(6)"  ::: "memory");
        else if (ahead == 1) asm volatile("s_waitcnt vmcnt(3)"  ::: "memory");
        else                 asm volatile("s_waitcnt vmcnt(0)"  ::: "memory");
        asm volatile("s_barrier" ::: "memory");

        const char* sa = (const char*)(sA + cur * 4096);
        const char* sb = (const char*)(sB + cur * 8192);
        v8s af[2], bfr[4][2];
        #pragma unroll
        for (int ks = 0; ks < 2; ++ks) {
            const int row = wm + l15;
            const int ch  = ks * 4 + lq;
            af[ks] = *(const v8s*)(sa + row * 128 + (((ch ^ (row & 7))) << 4));
        }
        #pragma unroll
        for (int nf = 0; nf < 4; ++nf)
            #pragma unroll
            for (int ks = 0; ks < 2; ++ks) {
                const int row = wn + nf * 16 + l15;
                const int ch  = ks * 4 + lq;
                bfr[nf][ks] = *(const v8s*)(sb + row * 128 + (((ch ^ (row & 7))) << 4));
            }
        #pragma unroll
        for (int ks = 0; ks < 2; ++ks)
            #pragma unroll
            for (int nf = 0; nf < 4; ++nf)
                acc[nf] = __builtin_amdgcn_mfma_f32_16x16x32_bf16(
                    af[ks], bfr[nf][ks], acc[nf], 0, 0, 0);
        asm volatile("s_barrier" ::: "memory");

        cur = (cur + 1 == NBUF) ? 0 : cur + 1;
        stg = (stg + 1 == NBUF) ? 0 : stg + 1;
    }

    // ---- epilogue: gates -> LDS, then cell (c in registers) ----
    float* sG = (float*)smem;   // [64][132] f32 = 33792B (reuses staging LDS)
    #pragma unroll
    for (int nf = 0; nf < 4; ++nf)
        #pragma unroll
        for (int r = 0; r < 4; ++r)
            sG[(wm + lq * 4 + r) * 132 + wn + nf * 16 + l15] = acc[nf][r];
    __syncthreads();

    const int erow = tid >> 3;           // 0..63
    const int jj   = (tid & 7) * 4;      // 0,4,..,28
    const int gb   = bm + erow;
    const float* sGr = sG + erow * 132;
    v4f n0;
    u16 hv[4];
    #pragma unroll
    for (int q = 0; q < 4; ++q) {
        const float gi = sGr[      jj + q];
        const float gf = sGr[32  + jj + q];
        const float gg = sGr[64  + jj + q];
        const float go = sGr[96  + jj + q];
        const float cv = cc[q];
        const float ii = 1.f / (1.f + __expf(-gi));
        const float ff = 1.f / (1.f + __expf(-gf));
        const float g2 = tanhf(gg);
        const float oo = 1.f / (1.f + __expf(-go));
        const float cq = ff * cv + ii * g2;
        n0[q] = cq;
        hv[q] = f2bf(oo * tanhf(cq));
    }
    cc = n0;
    // h writes: agent-scope atomic u32 stores (write-through; no stale copies)
    unsigned int* d1 = (unsigned int*)(h1 + (size_t)gb * h1s + j0 + jj);
    #pragma unroll
    for (int w2 = 0; w2 < 2; ++w2) {
        unsigned int val = (unsigned int)hv[2 * w2] | ((unsigned int)hv[2 * w2 + 1] << 16);
        st_agent_u32(d1 + w2, val);
    }
    if (h2) {
        unsigned int* d2 = (unsigned int*)(h2 + (size_t)gb * h2s + j0 + jj);
        #pragma unroll
        for (int w2 = 0; w2 < 2; ++w2) {
            unsigned int val = (unsigned int)hv[2 * w2] | ((unsigned int)hv[2 * w2 + 1] << 16);
            st_agent_u32(d2 + w2, val);
        }
    }
}

// ---- FC 1024->96 + hardtanh; 2 batch rows per block (512 threads) ----
__device__ __forceinline__ void fc_stage(
    char* smem, const u16* __restrict__ h2, int h2s,
    const u16* __restrict__ w, const float* __restrict__ fcb,
    float* __restrict__ out, u16* __restrict__ xdst, int t, int id)
{
    float* sh = (float*)smem;            // [2][1024] f32
    const int tid  = threadIdx.x;
    const int half = tid >> 8;           // 0,1
    const int htid = tid & 255;
    const int b    = id * 2 + half;      // 0..511
    // h2 written cross-block since last sync -> coherence-point u32 loads
    const unsigned int* hp = (const unsigned int*)(h2 + (size_t)b * h2s + htid * 4);
    #pragma unroll
    for (int w4 = 0; w4 < 2; ++w4) {
        unsigned int u = ld_agent_u32(hp + w4);
        sh[half * H_DIM + htid * 4 + 2 * w4]     = bf2f((u16)(u & 0xffffu));
        sh[half * H_DIM + htid * 4 + 2 * w4 + 1] = bf2f((u16)(u >> 16));
    }
    __syncthreads();
    if (htid < IN_DIM) {
        const u16* wr = w + (size_t)htid * H_DIM;
        const float* shr = sh + half * H_DIM;
        float acc = fcb[htid];
        #pragma unroll 4
        for (int k = 0; k < H_DIM; k += 8) {
            v8u16 wv = *(const v8u16*)(wr + k);
            #pragma unroll
            for (int q = 0; q < 8; ++q) acc += shr[k + q] * bf2f(wv[q]);
        }
        acc = fminf(1.f, fmaxf(-1.f, acc));
        out[(size_t)b * (T_STEPS * IN_DIM) + t * IN_DIM + htid] = acc;
        // x write crosses the next sync: pair lanes -> one atomic u32 store
        float o2 = __shfl_xor(acc, 1);
        if ((htid & 1) == 0) {
            unsigned int val = (unsigned int)f2bf(acc) | ((unsigned int)f2bf(o2) << 16);
            st_agent_u32((unsigned int*)(xdst + (size_t)b * K0P + htid), val);
        }
    }
}

// ================= the persistent kernel =================
__global__ __launch_bounds__(512, 1) void lstm_all_k(
    const u16* __restrict__ w0, const u16* __restrict__ w1, const u16* __restrict__ w2,
    u16* A00, u16* A01, u16* A10, u16* A11, u16* A20, u16* A21,
    const u16* __restrict__ fcw, const float* __restrict__ bsum,
    const float* __restrict__ cells, const float* __restrict__ fcb,
    float* __restrict__ out, int* bar)
{
    __shared__ __align__(16) char smem[147456];   // 6x8KB A + 6x16KB W = 144KB

    const int tid  = threadIdx.x;
    const int lane = tid & 63;
    const int wid  = tid >> 6;
    const int wn   = (wid & 1) * 64;
    const int l15  = lane & 15;

    // XCD swizzle: 8 m-blocks sharing a W-panel land on one XCD;
    // 4 same-mblk blocks per XCD share the A slab through that XCD's L2.
    const int id    = blockIdx.x;
    const int panel = (id & 7) * 4 + (id >> 6);   // 0..31  (j-panel)
    const int mblk  = (id >> 3) & 7;              // 0..7
    const int bm    = mblk * 64;
    const int j0    = panel * 32;

    // per-layer bias (this thread's 4 nf columns)
    v4f bv0, bv1, bv2;
    #pragma unroll
    for (int nf = 0; nf < 4; ++nf) {
        const int ncol = wn + nf * 16 + l15;
        const int idx  = (ncol >> 5) * H_DIM + j0 + (ncol & 31);
        bv0[nf] = bsum[idx];
        bv1[nf] = bsum[GATES + idx];
        bv2[nf] = bsum[2 * GATES + idx];
    }

    // persistent c-state in registers: this thread owns c[layer][gb][j0+jj..+3]
    const int erow = tid >> 3;
    const int jj   = (tid & 7) * 4;
    const int gb   = bm + erow;
    v4f c0, c1, c2;
    {
        const float* cr = cells + (size_t)gb * H_DIM + j0 + jj;
        c0 = *(const v4f*)cr;
        cr += (size_t)BATCH * H_DIM;
        c1 = *(const v4f*)cr;
        cr += (size_t)BATCH * H_DIM;
        c2 = *(const v4f*)cr;
    }

    int g = 0;
    #pragma unroll 1
    for (int t = 0; t < T_STEPS; ++t) {
        const int pr = t & 1;
        u16* A0r = pr ? A01 : A00;  u16* A0w = pr ? A00 : A01;
        u16* A1r = pr ? A11 : A10;  u16* A1w = pr ? A10 : A11;
        u16* A2r = pr ? A21 : A20;  u16* A2w = pr ? A20 : A21;

        // layer 0: reads [x(t)|h0(t-1)]; h0 -> own next-parity slot + layer1 x
        gemm_stage(smem, A0r, w0, K0P, K0P / 64, bv0, c0,
                   A0w + IN_DIM, K0P, A1r, K12, bm, j0);
        grid_sync(bar, ++g, false);
        // layer 1
        gemm_stage(smem, A1r, w1, K12, K12 / 64, bv1, c1,
                   A1w + H_DIM, K12, A2r, K12, bm, j0);
        grid_sync(bar, ++g, false);
        // layer 2
        gemm_stage(smem, A2r, w2, K12, K12 / 64, bv2, c2,
                   A2w + H_DIM, K12, (u16*)nullptr, 0, bm, j0);
        grid_sync(bar, ++g, false);
        // FC: reads h2(t) (parity pn), writes out[:,t,:] and x(t+1)
        fc_stage(smem, A2w + H_DIM, K12, fcw, fcb, out, A0w, t, id);
        grid_sync(bar, ++g, true);   // per-step acquire (inv) lives here
    }
}

// ================= prologue =================
__global__ __launch_bounds__(256) void convpack_k(
    const float* __restrict__ src, int srcStride,
    u16* __restrict__ dst, int dstStride, int cols8, long total8)
{
    long i = (long)blockIdx.x * 256 + threadIdx.x;
    if (i >= total8) return;
    const int r  = (int)(i / cols8);
    const int cc = (int)(i - (long)r * cols8) * 8;
    const float* s = src + (size_t)r * srcStride + cc;
    v4f a = *(const v4f*)s;
    v4f b = *(const v4f*)(s + 4);
    v8u16 o;
    #pragma unroll
    for (int q = 0; q < 4; ++q) { o[q] = f2bf(a[q]); o[4 + q] = f2bf(b[q]); }
    *(v8u16*)(dst + (size_t)r * dstStride + cc) = o;
}

__global__ __launch_bounds__(256) void zero16_k(
    u16* __restrict__ dst, int dstStride, int cols8, long total8)
{
    long i = (long)blockIdx.x * 256 + threadIdx.x;
    if (i >= total8) return;
    const int r  = (int)(i / cols8);
    const int cc = (int)(i - (long)r * cols8) * 8;
    v8u16 z = {0, 0, 0, 0, 0, 0, 0, 0};
    *(v8u16*)(dst + (size_t)r * dstStride + cc) = z;
}

__global__ __launch_bounds__(256) void add_k(
    const float* __restrict__ a, const float* __restrict__ b,
    float* __restrict__ o, int n)
{
    int i = blockIdx.x * 256 + threadIdx.x;
    if (i < n) o[i] = a[i] + b[i];
}

extern "C" void kernel_launch(void* const* d_in, const int* in_sizes, int n_in,
                              void* d_out, int out_size, void* d_ws, size_t ws_size,
                              hipStream_t stream)
{
    const float* inputs  = (const float*)d_in[0];
    const float* hiddens = (const float*)d_in[1];
    const float* cells   = (const float*)d_in[2];
    const float* Wih[3]  = {(const float*)d_in[3], (const float*)d_in[7],  (const float*)d_in[11]};
    const float* Whh[3]  = {(const float*)d_in[4], (const float*)d_in[8],  (const float*)d_in[12]};
    const float* bih[3]  = {(const float*)d_in[5], (const float*)d_in[9],  (const float*)d_in[13]};
    const float* bhh[3]  = {(const float*)d_in[6], (const float*)d_in[10], (const float*)d_in[14]};
    const float* fc_w    = (const float*)d_in[15];
    const float* fc_b    = (const float*)d_in[16];
    float* out = (float*)d_out;

    // ---- workspace carve-up ----
    char* p = (char*)d_ws;
    auto take = [&](size_t bytes) -> void* {
        void* r = p; p += (bytes + 255) & ~(size_t)255; return r;
    };
    const int Kl[3]  = {K0P, K12, K12};
    const int Kin[3] = {IN_DIM, H_DIM, H_DIM};
    u16* wcat[3];
    for (int l = 0; l < 3; ++l) wcat[l] = (u16*)take((size_t)GATES * Kl[l] * 2);
    u16* Ab[3][2];
    for (int l = 0; l < 3; ++l)
        for (int q = 0; q < 2; ++q) Ab[l][q] = (u16*)take((size_t)BATCH * Kl[l] * 2);
    u16*   fcwb = (u16*)take((size_t)IN_DIM * H_DIM * 2);
    float* bsum = (float*)take((size_t)3 * GATES * 4);
    int*   bar  = (int*)take(8192);
    if ((size_t)(p - (char*)d_ws) > ws_size) return;

    auto pack = [&](const float* s, int ss, u16* d, int ds, int rows, int cols) {
        long t8 = (long)rows * (cols / 8);
        convpack_k<<<(int)((t8 + 255) / 256), 256, 0, stream>>>(s, ss, d, ds, cols / 8, t8);
    };
    auto zero = [&](u16* d, int ds, int rows, int cols) {
        long t8 = (long)rows * (cols / 8);
        zero16_k<<<(int)((t8 + 255) / 256), 256, 0, stream>>>(d, ds, cols / 8, t8);
    };

    // weights -> bf16 concatenated [Wih | Whh | pad]
    for (int l = 0; l < 3; ++l) {
        pack(Wih[l], Kin[l], wcat[l],           Kl[l], GATES, Kin[l]);
        pack(Whh[l], H_DIM,  wcat[l] + Kin[l],  Kl[l], GATES, H_DIM);
    }
    zero(wcat[0] + IN_DIM + H_DIM, K0P, GATES, K0P - IN_DIM - H_DIM);
    pack(fc_w, H_DIM, fcwb, H_DIM, IN_DIM, H_DIM);

    // initial states (parity 0), x0, pads (both parities of layer0)
    for (int l = 0; l < 3; ++l)
        pack(hiddens + (size_t)l * BATCH * H_DIM, H_DIM,
             Ab[l][0] + Kin[l], Kl[l], BATCH, H_DIM);
    pack(inputs, T_STEPS * IN_DIM, Ab[0][0], K0P, BATCH, IN_DIM);   // x_0
    zero(Ab[0][0] + IN_DIM + H_DIM, K0P, BATCH, K0P - IN_DIM - H_DIM);
    zero(Ab[0][1] + IN_DIM + H_DIM, K0P, BATCH, K0P - IN_DIM - H_DIM);

    for (int l = 0; l < 3; ++l)
        add_k<<<16, 256, 0, stream>>>(bih[l], bhh[l], bsum + l * GATES, GATES);
    hipMemsetAsync(bar, 0, 8192, stream);

    // ---- the whole recurrence: one persistent kernel, plain launch ----
    lstm_all_k<<<NBLK, 512, 0, stream>>>(
        wcat[0], wcat[1], wcat[2],
        Ab[0][0], Ab[0][1], Ab[1][0], Ab[1][1], Ab[2][0], Ab[2][1],
        fcwb, bsum, cells, fc_b, out,
        bar);
}

// Round 12
// 4506.590 us; speedup vs baseline: 1.0267x; 1.0267x over previous
//
#include <hip/hip_runtime.h>
#include <cstdint>
#include <cstddef>

// Autoregressive 3-layer LSTM, B=512, T=75, IN=96, H=1024, bf16 MFMA compute.
// R12: BK=128 (half the K-iterations) on the R10 skeleton.
//   R8-R11 post-mortems: prefetch depth, coherence policy, TLP>2waves, barrier
//   protocol all neutral/regressive -> the invariant cost is PER-ITERATION
//   overhead (2 barriers + vmcnt + ~400cyc/CU VALU addr math + LDS-DMA issue
//   x 82 iters/step). BK 64->128 halves iteration count: 41 iters/step.
//   - 3-buffer ring (A 16KB + W 32KB per buf = 144KB LDS, R11-proven size),
//     prefetch depth 2, counted vmcnt 12/6/0.
//   - Staging source offsets precomputed once (6/thread), k0 added per iter.
//   - Swizzle: 16 chunks/row, chunk ^= row&15 (2 lanes/bank-group = free).
//   Memory scheme unchanged from R10: cached A+W, per-step acquire fence at
//   FC sync, write-through agent-atomic h/x, fence-free two-level barrier,
//   512 thr (2 waves/SIMD), c-state in registers.

typedef unsigned short u16;
typedef float v4f __attribute__((ext_vector_type(4)));
typedef short v8s __attribute__((ext_vector_type(8)));    // 8 bf16 (4 VGPRs)
typedef u16   v8u16 __attribute__((ext_vector_type(8)));

#define BATCH 512
#define H_DIM 1024
#define GATES 4096
#define T_STEPS 75
#define IN_DIM 96
#define K0P 1152              // layer0 K padded: 96 + 1024 + 32 zeros (9x128)
#define K12 2048              // layers 1,2 K: 1024 + 1024 (16x128)
#define NBLK 256
#define BUFB 49152            // bytes per ring buffer: A 16KB + W 32KB

__device__ __forceinline__ float bf2f(u16 u) {
    unsigned int x = ((unsigned int)u) << 16;
    return __builtin_bit_cast(float, x);
}
__device__ __forceinline__ u16 f2bf(float f) {   // round-to-nearest-even
    unsigned int x = __builtin_bit_cast(unsigned int, f);
    x += 0x7fffu + ((x >> 16) & 1u);
    return (u16)(x >> 16);
}
// cached global->LDS (W: x8 panel dedup; A: x4 m-block dedup per XCD)
__device__ __forceinline__ void gload16(const void* g, void* l) {
    __builtin_amdgcn_global_load_lds(
        (const __attribute__((address_space(1))) void*)g,
        (__attribute__((address_space(3))) void*)l, 16, 0, 0);
}
__device__ __forceinline__ void st_agent_u32(unsigned int* p, unsigned int v) {
    __hip_atomic_store(p, v, __ATOMIC_RELAXED, __HIP_MEMORY_SCOPE_AGENT);
}
__device__ __forceinline__ unsigned int ld_agent_u32(const unsigned int* p) {
    return __hip_atomic_load(p, __ATOMIC_RELAXED, __HIP_MEMORY_SCOPE_AGENT);
}

// ---- two-level grid barrier, contention-separated (R7, proven) ----
__device__ __forceinline__ void grid_sync(int* bar, int g, bool acq) {
    __syncthreads();   // all waves: s_waitcnt vmcnt(0) -> stores visible
    if (threadIdx.x == 0) {
        int old = __hip_atomic_fetch_add(&bar[(blockIdx.x & 7) * 32], 1,
                                         __ATOMIC_RELAXED, __HIP_MEMORY_SCOPE_AGENT);
        if (old + 1 == 32 * g) {            // this block completed its group
            int r = __hip_atomic_fetch_add(&bar[256], 1,
                                           __ATOMIC_RELAXED, __HIP_MEMORY_SCOPE_AGENT);
            if (r + 1 == 8 * g)             // all groups complete
                __hip_atomic_store(&bar[288], g,
                                   __ATOMIC_RELAXED, __HIP_MEMORY_SCOPE_AGENT);
        }
        int spins = 0;
        while (__hip_atomic_load(&bar[288],
                                 __ATOMIC_RELAXED, __HIP_MEMORY_SCOPE_AGENT) < g) {
            if (++spins > (1 << 17)) break;   // watchdog: fail fast, not hang
            __builtin_amdgcn_s_sleep(1);
        }
        if (acq)
            __builtin_amdgcn_fence(__ATOMIC_ACQUIRE, "agent");   // inv L1/L2
    }
    __syncthreads();
}

// ---- fused gates-GEMM + LSTM cell stage ----
// block tile 64 rows x (4 gates x 32 j), 8 waves (4m x 2n), BK=128.
// LDS per buffer: A [64][128] u16 (16KB) then W [128][128] u16 (32KB).
__device__ __forceinline__ void gemm_stage(
    char* smem, const u16* __restrict__ A, const u16* __restrict__ W,
    int K, int nk, v4f bv, v4f& cc,
    u16* __restrict__ h1, int h1s, u16* __restrict__ h2, int h2s,
    int bm, int j0)
{
    const int tid  = threadIdx.x;
    const int lane = tid & 63;
    const int wid  = tid >> 6;          // 0..7
    const int wm   = (wid >> 1) * 16;   // wave m-offset: 0,16,32,48
    const int wn   = (wid & 1) * 64;    // wave n-offset: 0,64
    const int l15  = lane & 15;
    const int lq   = lane >> 4;         // 0..3

    v4f acc[4];
    #pragma unroll
    for (int nf = 0; nf < 4; ++nf) {
        v4f tv = {bv[nf], bv[nf], bv[nf], bv[nf]};
        acc[nf] = tv;
    }

    // Precomputed staging offsets. 16B chunk n = row*16 + chunk.
    // A: 1024 chunks (2/thread); W: 2048 chunks (4/thread).
    // Source column pre-swizzled: chunk c holds global k-chunk c^(row&15).
    size_t asrc[2]; int adst[2];
    #pragma unroll
    for (int j = 0; j < 2; ++j) {
        const int n = j * 512 + tid, r = n >> 4, c = n & 15;
        asrc[j] = (size_t)(bm + r) * K + ((c ^ (r & 15)) << 3);
        adst[j] = n * 8;                 // u16 units
    }
    size_t wsrc[4]; int wdst[4];
    #pragma unroll
    for (int j = 0; j < 4; ++j) {
        const int n = j * 512 + tid, r = n >> 4, c = n & 15;
        wsrc[j] = (size_t)((r >> 5) * H_DIM + j0 + (r & 31)) * K + ((c ^ (r & 15)) << 3);
        wdst[j] = n * 8;
    }

    auto stage = [&](int b, int k0) {
        u16* sa = (u16*)(smem + b * BUFB);
        u16* sb = (u16*)(smem + b * BUFB + 16384);
        #pragma unroll
        for (int j = 0; j < 2; ++j) gload16(A + asrc[j] + k0, sa + adst[j]);
        #pragma unroll
        for (int j = 0; j < 4; ++j) gload16(W + wsrc[j] + k0, sb + wdst[j]);
    };

    // depth-2 prologue
    stage(0, 0);
    if (nk > 1) stage(1, 128);

    int cur = 0, stg = 2;
    #pragma unroll 1
    for (int tt = 0; tt < nk; ++tt) {
        if (tt + 2 < nk) stage(stg, (tt + 2) * 128);
        const int ahead = (nk - 1 - tt) < 2 ? (nk - 1 - tt) : 2;
        if (ahead == 2)      asm volatile("s_waitcnt vmcnt(12)" ::: "memory");
        else if (ahead == 1) asm volatile("s_waitcnt vmcnt(6)"  ::: "memory");
        else                 asm volatile("s_waitcnt vmcnt(0)"  ::: "memory");
        asm volatile("s_barrier" ::: "memory");

        const char* sa = (const char*)(smem + cur * BUFB);
        const char* sb = sa + 16384;
        v8s af[4], bfr[4][4];
        #pragma unroll
        for (int ks = 0; ks < 4; ++ks) {
            const int row = wm + l15;
            const int ch  = ks * 4 + lq;
            af[ks] = *(const v8s*)(sa + row * 256 + (((ch ^ (row & 15))) << 4));
        }
        #pragma unroll
        for (int nf = 0; nf < 4; ++nf)
            #pragma unroll
            for (int ks = 0; ks < 4; ++ks) {
                const int row = wn + nf * 16 + l15;
                const int ch  = ks * 4 + lq;
                bfr[nf][ks] = *(const v8s*)(sb + row * 256 + (((ch ^ (row & 15))) << 4));
            }
        #pragma unroll
        for (int ks = 0; ks < 4; ++ks)
            #pragma unroll
            for (int nf = 0; nf < 4; ++nf)
                acc[nf] = __builtin_amdgcn_mfma_f32_16x16x32_bf16(
                    af[ks], bfr[nf][ks], acc[nf], 0, 0, 0);
        asm volatile("s_barrier" ::: "memory");

        cur = (cur + 1 == 3) ? 0 : cur + 1;
        stg = (stg + 1 == 3) ? 0 : stg + 1;
    }

    // ---- epilogue: gates -> LDS, then cell (c in registers) ----
    float* sG = (float*)smem;   // [64][132] f32 = 33792B (reuses staging LDS)
    #pragma unroll
    for (int nf = 0; nf < 4; ++nf)
        #pragma unroll
        for (int r = 0; r < 4; ++r)
            sG[(wm + lq * 4 + r) * 132 + wn + nf * 16 + l15] = acc[nf][r];
    __syncthreads();

    const int erow = tid >> 3;           // 0..63
    const int jj   = (tid & 7) * 4;      // 0,4,..,28
    const int gb   = bm + erow;
    const float* sGr = sG + erow * 132;
    v4f n0;
    u16 hv[4];
    #pragma unroll
    for (int q = 0; q < 4; ++q) {
        const float gi = sGr[      jj + q];
        const float gf = sGr[32  + jj + q];
        const float gg = sGr[64  + jj + q];
        const float go = sGr[96  + jj + q];
        const float cv = cc[q];
        const float ii = 1.f / (1.f + __expf(-gi));
        const float ff = 1.f / (1.f + __expf(-gf));
        const float g2 = tanhf(gg);
        const float oo = 1.f / (1.f + __expf(-go));
        const float cq = ff * cv + ii * g2;
        n0[q] = cq;
        hv[q] = f2bf(oo * tanhf(cq));
    }
    cc = n0;
    // h writes: agent-scope atomic u32 stores (write-through; no stale copies)
    unsigned int* d1 = (unsigned int*)(h1 + (size_t)gb * h1s + j0 + jj);
    #pragma unroll
    for (int w2 = 0; w2 < 2; ++w2) {
        unsigned int val = (unsigned int)hv[2 * w2] | ((unsigned int)hv[2 * w2 + 1] << 16);
        st_agent_u32(d1 + w2, val);
    }
    if (h2) {
        unsigned int* d2 = (unsigned int*)(h2 + (size_t)gb * h2s + j0 + jj);
        #pragma unroll
        for (int w2 = 0; w2 < 2; ++w2) {
            unsigned int val = (unsigned int)hv[2 * w2] | ((unsigned int)hv[2 * w2 + 1] << 16);
            st_agent_u32(d2 + w2, val);
        }
    }
}

// ---- FC 1024->96 + hardtanh; 2 batch rows per block (512 threads) ----
__device__ __forceinline__ void fc_stage(
    char* smem, const u16* __restrict__ h2, int h2s,
    const u16* __restrict__ w, const float* __restrict__ fcb,
    float* __restrict__ out, u16* __restrict__ xdst, int t, int id)
{
    float* sh = (float*)smem;            // [2][1024] f32
    const int tid  = threadIdx.x;
    const int half = tid >> 8;           // 0,1
    const int htid = tid & 255;
    const int b    = id * 2 + half;      // 0..511
    // h2 written cross-block since last sync -> coherence-point u32 loads
    const unsigned int* hp = (const unsigned int*)(h2 + (size_t)b * h2s + htid * 4);
    #pragma unroll
    for (int w4 = 0; w4 < 2; ++w4) {
        unsigned int u = ld_agent_u32(hp + w4);
        sh[half * H_DIM + htid * 4 + 2 * w4]     = bf2f((u16)(u & 0xffffu));
        sh[half * H_DIM + htid * 4 + 2 * w4 + 1] = bf2f((u16)(u >> 16));
    }
    __syncthreads();
    if (htid < IN_DIM) {
        const u16* wr = w + (size_t)htid * H_DIM;
        const float* shr = sh + half * H_DIM;
        float acc = fcb[htid];
        #pragma unroll 4
        for (int k = 0; k < H_DIM; k += 8) {
            v8u16 wv = *(const v8u16*)(wr + k);
            #pragma unroll
            for (int q = 0; q < 8; ++q) acc += shr[k + q] * bf2f(wv[q]);
        }
        acc = fminf(1.f, fmaxf(-1.f, acc));
        out[(size_t)b * (T_STEPS * IN_DIM) + t * IN_DIM + htid] = acc;
        // x write crosses the next sync: pair lanes -> one atomic u32 store
        float o2 = __shfl_xor(acc, 1);
        if ((htid & 1) == 0) {
            unsigned int val = (unsigned int)f2bf(acc) | ((unsigned int)f2bf(o2) << 16);
            st_agent_u32((unsigned int*)(xdst + (size_t)b * K0P + htid), val);
        }
    }
}

// ================= the persistent kernel =================
__global__ __launch_bounds__(512, 1) void lstm_all_k(
    const u16* __restrict__ w0, const u16* __restrict__ w1, const u16* __restrict__ w2,
    u16* A00, u16* A01, u16* A10, u16* A11, u16* A20, u16* A21,
    const u16* __restrict__ fcw, const float* __restrict__ bsum,
    const float* __restrict__ cells, const float* __restrict__ fcb,
    float* __restrict__ out, int* bar)
{
    __shared__ __align__(16) char smem[147456];   // 3 ring bufs x 48KB

    const int tid  = threadIdx.x;
    const int lane = tid & 63;
    const int wid  = tid >> 6;
    const int wn   = (wid & 1) * 64;
    const int l15  = lane & 15;

    // XCD swizzle: 8 m-blocks sharing a W-panel land on one XCD;
    // 4 same-mblk blocks per XCD share the A slab through that XCD's L2.
    const int id    = blockIdx.x;
    const int panel = (id & 7) * 4 + (id >> 6);   // 0..31  (j-panel)
    const int mblk  = (id >> 3) & 7;              // 0..7
    const int bm    = mblk * 64;
    const int j0    = panel * 32;

    // per-layer bias (this thread's 4 nf columns)
    v4f bv0, bv1, bv2;
    #pragma unroll
    for (int nf = 0; nf < 4; ++nf) {
        const int ncol = wn + nf * 16 + l15;
        const int idx  = (ncol >> 5) * H_DIM + j0 + (ncol & 31);
        bv0[nf] = bsum[idx];
        bv1[nf] = bsum[GATES + idx];
        bv2[nf] = bsum[2 * GATES + idx];
    }

    // persistent c-state in registers: this thread owns c[layer][gb][j0+jj..+3]
    const int erow = tid >> 3;
    const int jj   = (tid & 7) * 4;
    const int gb   = bm + erow;
    v4f c0, c1, c2;
    {
        const float* cr = cells + (size_t)gb * H_DIM + j0 + jj;
        c0 = *(const v4f*)cr;
        cr += (size_t)BATCH * H_DIM;
        c1 = *(const v4f*)cr;
        cr += (size_t)BATCH * H_DIM;
        c2 = *(const v4f*)cr;
    }

    int g = 0;
    #pragma unroll 1
    for (int t = 0; t < T_STEPS; ++t) {
        const int pr = t & 1;
        u16* A0r = pr ? A01 : A00;  u16* A0w = pr ? A00 : A01;
        u16* A1r = pr ? A11 : A10;  u16* A1w = pr ? A10 : A11;
        u16* A2r = pr ? A21 : A20;  u16* A2w = pr ? A20 : A21;

        // layer 0: reads [x(t)|h0(t-1)]; h0 -> own next-parity slot + layer1 x
        gemm_stage(smem, A0r, w0, K0P, K0P / 128, bv0, c0,
                   A0w + IN_DIM, K0P, A1r, K12, bm, j0);
        grid_sync(bar, ++g, false);
        // layer 1
        gemm_stage(smem, A1r, w1, K12, K12 / 128, bv1, c1,
                   A1w + H_DIM, K12, A2r, K12, bm, j0);
        grid_sync(bar, ++g, false);
        // layer 2
        gemm_stage(smem, A2r, w2, K12, K12 / 128, bv2, c2,
                   A2w + H_DIM, K12, (u16*)nullptr, 0, bm, j0);
        grid_sync(bar, ++g, false);
        // FC: reads h2(t) (parity pn), writes out[:,t,:] and x(t+1)
        fc_stage(smem, A2w + H_DIM, K12, fcw, fcb, out, A0w, t, id);
        grid_sync(bar, ++g, true);   // per-step acquire (inv) lives here
    }
}

// ================= prologue =================
__global__ __launch_bounds__(256) void convpack_k(
    const float* __restrict__ src, int srcStride,
    u16* __restrict__ dst, int dstStride, int cols8, long total8)
{
    long i = (long)blockIdx.x * 256 + threadIdx.x;
    if (i >= total8) return;
    const int r  = (int)(i / cols8);
    const int cc = (int)(i - (long)r * cols8) * 8;
    const float* s = src + (size_t)r * srcStride + cc;
    v4f a = *(const v4f*)s;
    v4f b = *(const v4f*)(s + 4);
    v8u16 o;
    #pragma unroll
    for (int q = 0; q < 4; ++q) { o[q] = f2bf(a[q]); o[4 + q] = f2bf(b[q]); }
    *(v8u16*)(dst + (size_t)r * dstStride + cc) = o;
}

__global__ __launch_bounds__(256) void zero16_k(
    u16* __restrict__ dst, int dstStride, int cols8, long total8)
{
    long i = (long)blockIdx.x * 256 + threadIdx.x;
    if (i >= total8) return;
    const int r  = (int)(i / cols8);
    const int cc = (int)(i - (long)r * cols8) * 8;
    v8u16 z = {0, 0, 0, 0, 0, 0, 0, 0};
    *(v8u16*)(dst + (size_t)r * dstStride + cc) = z;
}

__global__ __launch_bounds__(256) void add_k(
    const float* __restrict__ a, const float* __restrict__ b,
    float* __restrict__ o, int n)
{
    int i = blockIdx.x * 256 + threadIdx.x;
    if (i < n) o[i] = a[i] + b[i];
}

extern "C" void kernel_launch(void* const* d_in, const int* in_sizes, int n_in,
                              void* d_out, int out_size, void* d_ws, size_t ws_size,
                              hipStream_t stream)
{
    const float* inputs  = (const float*)d_in[0];
    const float* hiddens = (const float*)d_in[1];
    const float* cells   = (const float*)d_in[2];
    const float* Wih[3]  = {(const float*)d_in[3], (const float*)d_in[7],  (const float*)d_in[11]};
    const float* Whh[3]  = {(const float*)d_in[4], (const float*)d_in[8],  (const float*)d_in[12]};
    const float* bih[3]  = {(const float*)d_in[5], (const float*)d_in[9],  (const float*)d_in[13]};
    const float* bhh[3]  = {(const float*)d_in[6], (const float*)d_in[10], (const float*)d_in[14]};
    const float* fc_w    = (const float*)d_in[15];
    const float* fc_b    = (const float*)d_in[16];
    float* out = (float*)d_out;

    // ---- workspace carve-up ----
    char* p = (char*)d_ws;
    auto take = [&](size_t bytes) -> void* {
        void* r = p; p += (bytes + 255) & ~(size_t)255; return r;
    };
    const int Kl[3]  = {K0P, K12, K12};
    const int Kin[3] = {IN_DIM, H_DIM, H_DIM};
    u16* wcat[3];
    for (int l = 0; l < 3; ++l) wcat[l] = (u16*)take((size_t)GATES * Kl[l] * 2);
    u16* Ab[3][2];
    for (int l = 0; l < 3; ++l)
        for (int q = 0; q < 2; ++q) Ab[l][q] = (u16*)take((size_t)BATCH * Kl[l] * 2);
    u16*   fcwb = (u16*)take((size_t)IN_DIM * H_DIM * 2);
    float* bsum = (float*)take((size_t)3 * GATES * 4);
    int*   bar  = (int*)take(8192);
    if ((size_t)(p - (char*)d_ws) > ws_size) return;

    auto pack = [&](const float* s, int ss, u16* d, int ds, int rows, int cols) {
        long t8 = (long)rows * (cols / 8);
        convpack_k<<<(int)((t8 + 255) / 256), 256, 0, stream>>>(s, ss, d, ds, cols / 8, t8);
    };
    auto zero = [&](u16* d, int ds, int rows, int cols) {
        long t8 = (long)rows * (cols / 8);
        zero16_k<<<(int)((t8 + 255) / 256), 256, 0, stream>>>(d, ds, cols / 8, t8);
    };

    // weights -> bf16 concatenated [Wih | Whh | pad]
    for (int l = 0; l < 3; ++l) {
        pack(Wih[l], Kin[l], wcat[l],           Kl[l], GATES, Kin[l]);
        pack(Whh[l], H_DIM,  wcat[l] + Kin[l],  Kl[l], GATES, H_DIM);
    }
    zero(wcat[0] + IN_DIM + H_DIM, K0P, GATES, K0P - IN_DIM - H_DIM);
    pack(fc_w, H_DIM, fcwb, H_DIM, IN_DIM, H_DIM);

    // initial states (parity 0), x0, pads (both parities of layer0)
    for (int l = 0; l < 3; ++l)
        pack(hiddens + (size_t)l * BATCH * H_DIM, H_DIM,
             Ab[l][0] + Kin[l], Kl[l], BATCH, H_DIM);
    pack(inputs, T_STEPS * IN_DIM, Ab[0][0], K0P, BATCH, IN_DIM);   // x_0
    zero(Ab[0][0] + IN_DIM + H_DIM, K0P, BATCH, K0P - IN_DIM - H_DIM);
    zero(Ab[0][1] + IN_DIM + H_DIM, K0P, BATCH, K0P - IN_DIM - H_DIM);

    for (int l = 0; l < 3; ++l)
        add_k<<<16, 256, 0, stream>>>(bih[l], bhh[l], bsum + l * GATES, GATES);
    hipMemsetAsync(bar, 0, 8192, stream);

    // ---- the whole recurrence: one persistent kernel, plain launch ----
    lstm_all_k<<<NBLK, 512, 0, stream>>>(
        wcat[0], wcat[1], wcat[2],
        Ab[0][0], Ab[0][1], Ab[1][0], Ab[1][1], Ab[2][0], Ab[2][1],
        fcwb, bsum, cells, fc_b, out,
        bar);
}